// Round 2
// baseline (86.027 us; speedup 1.0000x reference)
//
#include <hip/hip_runtime.h>
#include <math.h>

#define D    32
#define PREV 64
#define HID  128
#define HDIM 64

#define MB_BATCH   64     // batches per main block (one per lane)
#define MB_THREADS 512    // 8 waves
#define NWAVE      8
#define HPW        (HID / NWAVE)   // 16 h per wave

// ws float layout (all regions fully rewritten by prep every call):
//   [0,4096)      M[h*32+d]   = sum_p w1[d,p]*bw[h,p]
//   [4096,4224)   sbias[h]    = b1.bw[h,:] + bb[h]
//   [8192,12288)  w2T[h*32+d] = w2[d,h]

// grid 17 x 128 -- UNCHANGED (verified). Blocks 0..15: block b owns d in
// {2b,2b+1} -> 128 hw2 rows -> M columns + w2T columns. Block 16: b1 + sbias.
__global__ __launch_bounds__(128) void prep_kernel(
    const float* __restrict__ t,
    const float* __restrict__ hw1,
    const float* __restrict__ hb1,
    const float* __restrict__ hw2,
    const float* __restrict__ hb2,
    const float* __restrict__ bw,
    const float* __restrict__ bb,
    const float* __restrict__ w2,
    float* __restrict__ ws)
{
    __shared__ float hcode[HDIM];
    __shared__ float w1s[2][64];
    __shared__ float b1s[PREV];

    const int tid = threadIdx.x;
    const int blk = blockIdx.x;

    if (tid < HDIM) hcode[tid] = tanhf(t[0] * hw1[tid] + hb1[tid]);
    __syncthreads();

    if (blk < 16) {
        const int i = blk * 128 + tid;
        {
            const float4* row = reinterpret_cast<const float4*>(hw2 + (size_t)i * HDIM);
            float acc = hb2[i];
            #pragma unroll
            for (int q = 0; q < 16; ++q) {
                float4 u = row[q];
                int j = q * 4;
                acc += u.x * hcode[j] + u.y * hcode[j + 1]
                     + u.z * hcode[j + 2] + u.w * hcode[j + 3];
            }
            w1s[tid >> 6][tid & 63] = acc;
        }
        __syncthreads();

        for (int idx = tid; idx < 256; idx += 128) {
            const int h = idx & 127, dd = idx >> 7;
            const int d = 2 * blk + dd;
            const float4* bwr = reinterpret_cast<const float4*>(bw + h * PREV);
            const float* w1r = &w1s[dd][0];
            float acc = 0.f;
            #pragma unroll
            for (int q = 0; q < 16; ++q) {
                float4 u = bwr[q];
                int p = q * 4;
                acc += u.x * w1r[p]     + u.y * w1r[p + 1]
                     + u.z * w1r[p + 2] + u.w * w1r[p + 3];
            }
            ws[h * D + d] = acc;                    // M
            ws[8192 + h * D + d] = w2[d * HID + h]; // w2T
        }
    } else {
        if (tid < PREV) {
            const int i = 2048 + tid;
            const float4* row = reinterpret_cast<const float4*>(hw2 + (size_t)i * HDIM);
            float acc = hb2[i];
            #pragma unroll
            for (int q = 0; q < 16; ++q) {
                float4 u = row[q];
                int j = q * 4;
                acc += u.x * hcode[j] + u.y * hcode[j + 1]
                     + u.z * hcode[j + 2] + u.w * hcode[j + 3];
            }
            b1s[tid] = acc;
        }
        __syncthreads();
        {
            const float4* bwr = reinterpret_cast<const float4*>(bw + tid * PREV);
            float acc = bb[tid];
            #pragma unroll
            for (int q = 0; q < 16; ++q) {
                float4 u = bwr[q];
                int p = q * 4;
                acc += u.x * b1s[p]     + u.y * b1s[p + 1]
                     + u.z * b1s[p + 2] + u.w * b1s[p + 3];
            }
            ws[4096 + tid] = acc;
        }
    }
}

// grid 128 x 512 threads (8 waves). lane = batch (64 batches/block); each of
// the 8 waves owns 16 h's. At each h the M/W2T rows are wave-uniform ->
// scalar (SGPR) loads feed v_fma directly: NO per-lane weight traffic, no
// LDS in the hot loop. Partials (dx[32], div) combine via one small LDS
// buffer with conflict-free (lane+d)%32 banking.
__global__ __launch_bounds__(MB_THREADS) void main_kernel(
    const float* __restrict__ y,
    const float* __restrict__ ws,
    const float* __restrict__ b2,
    float* __restrict__ out)
{
    extern __shared__ float buf[];              // [NWAVE][MB_BATCH][33] = 67584 B
    __shared__ float xs[MB_BATCH][36];          // padded x rows, 16B-aligned rows
    __shared__ float sbias_s[HID];
    __shared__ float cs_s[HID];
    __shared__ float b2s[D];

    const int tid = threadIdx.x;
    const int blk = blockIdx.x;

    // ---- stage ----
    {   // y slice: 64*33 = 2112 contiguous floats = 528 float4, scatter into padded xs
        const float4* yb4 = reinterpret_cast<const float4*>(y + (size_t)blk * MB_BATCH * 33);
        for (int i = tid; i < 528; i += MB_THREADS) {
            float4 v = yb4[i];
            int base = 4 * i;
            int r0 = base / 33, c0 = base - 33 * r0;
            float vv[4] = { v.x, v.y, v.z, v.w };
            #pragma unroll
            for (int j = 0; j < 4; ++j) {
                int c = c0 + j, r = r0;
                if (c >= 33) { c -= 33; r += 1; }
                xs[r][c] = vv[j];   // col 32 = t-column, harmless (rows padded to 36)
            }
        }
    }
    if (tid < HID) {            // cs[h] = sum_d M[h,d]*w2T[h,d]
        const float4* mr = reinterpret_cast<const float4*>(ws + tid * D);
        const float4* wr = reinterpret_cast<const float4*>(ws + 8192 + tid * D);
        float acc = 0.f;
        #pragma unroll
        for (int q = 0; q < 8; ++q) {
            float4 m = mr[q], w = wr[q];
            acc += m.x * w.x + m.y * w.y + m.z * w.z + m.w * w.w;
        }
        cs_s[tid] = acc;
    } else if (tid < 2 * HID) {
        sbias_s[tid - HID] = ws[4096 + (tid - HID)];
    } else if (tid < 2 * HID + D) {
        b2s[tid - 2 * HID] = b2[tid - 2 * HID];
    }
    __syncthreads();

    const int lane = tid & 63;
    const int wid  = __builtin_amdgcn_readfirstlane(tid >> 6);  // force SGPR-uniform
    const int h0   = wid * HPW;

    // x into registers (per-lane row; 8x ds_read_b128, <=4-way alias)
    float x[D];
    {
        const float4* xr = reinterpret_cast<const float4*>(&xs[lane][0]);
        #pragma unroll
        for (int q = 0; q < 8; ++q) {
            float4 v = xr[q];
            x[4*q] = v.x; x[4*q+1] = v.y; x[4*q+2] = v.z; x[4*q+3] = v.w;
        }
    }

    float dx[D];
    #pragma unroll
    for (int d = 0; d < D; ++d) dx[d] = 0.f;
    float dv = 0.f;

    #pragma unroll
    for (int hi = 0; hi < HPW; ++hi) {
        const int h = h0 + hi;                         // uniform
        const float* __restrict__ Mr = ws + h * D;     // uniform base -> s_load
        const float* __restrict__ Wr = ws + 8192 + h * D;
        float p0 = 0.f, p1 = 0.f, p2 = 0.f, p3 = 0.f;  // 4 chains for FMA latency
        #pragma unroll
        for (int d = 0; d < D; d += 4) {
            p0 += Mr[d]     * x[d];
            p1 += Mr[d + 1] * x[d + 1];
            p2 += Mr[d + 2] * x[d + 2];
            p3 += Mr[d + 3] * x[d + 3];
        }
        float s = sbias_s[h] + ((p0 + p1) + (p2 + p3));
        // tanh(s) = 1 - 2/(e^{2s}+1); exact at both saturations
        float e = __expf(2.f * s);
        float a = 1.f - 2.f / (e + 1.f);
        dv += (1.f - a * a) * cs_s[h];
        #pragma unroll
        for (int d = 0; d < D; ++d)
            dx[d] += a * Wr[d];
    }

    // write this wave's partials: banks (lane+d)%32 -> conflict-free
    {
        float* my = buf + ((size_t)(wid * MB_BATCH) + lane) * 33;
        #pragma unroll
        for (int d = 0; d < D; ++d) my[d] = dx[d];
        my[D] = dv;
    }
    __syncthreads();

    // reduce 8 wave-partials -> block's 2112 contiguous outputs (coalesced)
    {
        float* ob = out + (size_t)blk * MB_BATCH * 33;
        for (int i = tid; i < MB_BATCH * 33; i += MB_THREADS) {
            float r = 0.f;
            #pragma unroll
            for (int w = 0; w < NWAVE; ++w)
                r += buf[w * (MB_BATCH * 33) + i];
            int c = i % 33;
            r = (c < 32) ? (r + b2s[c]) : -r;
            ob[i] = r;
        }
    }
}

extern "C" void kernel_launch(void* const* d_in, const int* in_sizes, int n_in,
                              void* d_out, int out_size, void* d_ws, size_t ws_size,
                              hipStream_t stream) {
    const float* y   = (const float*)d_in[0];
    const float* t   = (const float*)d_in[1];
    const float* hw1 = (const float*)d_in[2];
    const float* hb1 = (const float*)d_in[3];
    const float* hw2 = (const float*)d_in[4];
    const float* hb2 = (const float*)d_in[5];
    const float* bw  = (const float*)d_in[6];
    const float* bb  = (const float*)d_in[7];
    const float* w2  = (const float*)d_in[8];
    const float* b2  = (const float*)d_in[9];
    float* ws  = (float*)d_ws;
    float* out = (float*)d_out;

    hipLaunchKernelGGL(prep_kernel, dim3(17), dim3(128), 0, stream,
                       t, hw1, hb1, hw2, hb2, bw, bb, w2, ws);
    hipLaunchKernelGGL(main_kernel, dim3(8192 / MB_BATCH), dim3(MB_THREADS),
                       NWAVE * MB_BATCH * 33 * sizeof(float), stream,
                       y, ws, b2, out);
}

// Round 3
// 82.438 us; speedup vs baseline: 1.0435x; 1.0435x over previous
//
#include <hip/hip_runtime.h>
#include <math.h>

#define D    32
#define PREV 64
#define HID  128
#define HDIM 64
#define BPB  32      // batches per block (R1 had 16; halves ws re-read traffic)
#define TPB  512     // 8 waves -> same total wave count as R1 (2048)

// ws float layout (all regions fully rewritten by prep every call):
//   [0,4096)      M[h*32+d]   = sum_p w1[d,p]*bw[h,p]
//   [4096,4224)   sbias[h]    = b1.bw[h,:] + bb[h]
//   [8192,12288)  w2T[h*32+d] = w2[d,h]

// ---------------- DPP reduction helpers (verified in R1) ----------------
#define DPP_QUAD_XOR1   0xB1   // quad_perm(1,0,3,2)
#define DPP_QUAD_XOR2   0x4E   // quad_perm(2,3,0,1)
#define DPP_ROW_ROR4    0x124
#define DPP_ROW_ROR8    0x128
#define DPP_ROW_BCAST15 0x142

template <int CTRL>
__device__ __forceinline__ float dpp_radd(float v) {
    int t = __builtin_amdgcn_update_dpp(0, __float_as_int(v), CTRL, 0xF, 0xF, true);
    return v + __int_as_float(t);
}

// Sum over each 32-consecutive-lane group; lanes 16..31 (and 48..63) of the
// group hold the full 32-lane sum afterward.
__device__ __forceinline__ float reduce32(float v) {
    v = dpp_radd<DPP_QUAD_XOR1>(v);
    v = dpp_radd<DPP_QUAD_XOR2>(v);
    v = dpp_radd<DPP_ROW_ROR4>(v);
    v = dpp_radd<DPP_ROW_ROR8>(v);
    v = dpp_radd<DPP_ROW_BCAST15>(v);
    return v;
}

// grid 17 x 128 -- UNCHANGED (verified). Blocks 0..15: block b owns d in
// {2b,2b+1} -> 128 hw2 rows -> M columns + w2T columns. Block 16: b1 + sbias.
__global__ __launch_bounds__(128) void prep_kernel(
    const float* __restrict__ t,
    const float* __restrict__ hw1,
    const float* __restrict__ hb1,
    const float* __restrict__ hw2,
    const float* __restrict__ hb2,
    const float* __restrict__ bw,
    const float* __restrict__ bb,
    const float* __restrict__ w2,
    float* __restrict__ ws)
{
    __shared__ float hcode[HDIM];
    __shared__ float w1s[2][64];
    __shared__ float b1s[PREV];

    const int tid = threadIdx.x;
    const int blk = blockIdx.x;

    if (tid < HDIM) hcode[tid] = tanhf(t[0] * hw1[tid] + hb1[tid]);
    __syncthreads();

    if (blk < 16) {
        const int i = blk * 128 + tid;
        {
            const float4* row = reinterpret_cast<const float4*>(hw2 + (size_t)i * HDIM);
            float acc = hb2[i];
            #pragma unroll
            for (int q = 0; q < 16; ++q) {
                float4 u = row[q];
                int j = q * 4;
                acc += u.x * hcode[j] + u.y * hcode[j + 1]
                     + u.z * hcode[j + 2] + u.w * hcode[j + 3];
            }
            w1s[tid >> 6][tid & 63] = acc;
        }
        __syncthreads();

        for (int idx = tid; idx < 256; idx += 128) {
            const int h = idx & 127, dd = idx >> 7;
            const int d = 2 * blk + dd;
            const float4* bwr = reinterpret_cast<const float4*>(bw + h * PREV);
            const float* w1r = &w1s[dd][0];
            float acc = 0.f;
            #pragma unroll
            for (int q = 0; q < 16; ++q) {
                float4 u = bwr[q];
                int p = q * 4;
                acc += u.x * w1r[p]     + u.y * w1r[p + 1]
                     + u.z * w1r[p + 2] + u.w * w1r[p + 3];
            }
            ws[h * D + d] = acc;                    // M
            ws[8192 + h * D + d] = w2[d * HID + h]; // w2T
        }
    } else {
        if (tid < PREV) {
            const int i = 2048 + tid;
            const float4* row = reinterpret_cast<const float4*>(hw2 + (size_t)i * HDIM);
            float acc = hb2[i];
            #pragma unroll
            for (int q = 0; q < 16; ++q) {
                float4 u = row[q];
                int j = q * 4;
                acc += u.x * hcode[j] + u.y * hcode[j + 1]
                     + u.z * hcode[j + 2] + u.w * hcode[j + 3];
            }
            b1s[tid] = acc;
        }
        __syncthreads();
        {
            const float4* bwr = reinterpret_cast<const float4*>(bw + tid * PREV);
            float acc = bb[tid];
            #pragma unroll
            for (int q = 0; q < 16; ++q) {
                float4 u = bwr[q];
                int p = q * 4;
                acc += u.x * b1s[p]     + u.y * b1s[p + 1]
                     + u.z * b1s[p + 2] + u.w * b1s[p + 3];
            }
            ws[4096 + tid] = acc;
        }
    }
}

// grid 256 x 512 threads = 2048 waves (same as R1). Thread = (pair = tid>>5
// in 0..15, hg = tid&31). Each thread: 2 batches x 4 h. Ms/Ws staged ONCE per
// 32 batches (half of R1's ws traffic). Inner loop + DPP reduce identical to
// the verified R1 kernel.
__global__ __launch_bounds__(TPB) void main_kernel(
    const float* __restrict__ y,
    const float* __restrict__ ws,
    const float* __restrict__ b2,
    float* __restrict__ out)
{
    __shared__ float Ms[HID][36];
    __shared__ float Ws[HID][36];
    __shared__ float xs[BPB][36];
    __shared__ __align__(16) float os[BPB][33];  // flat 1056 floats, 16B-aligned
    __shared__ float sbias_s[HID];
    __shared__ float cs_s[HID];
    __shared__ float b2s[D];

    const int tid = threadIdx.x;
    const int blk = blockIdx.x;

    // ---- staging, all float4 ----
    // Ms/Ws: each 4096 floats = 1024 float4; 2 iters x 512 thr.
    {
        const float4* m4 = reinterpret_cast<const float4*>(ws);
        const float4* w4 = reinterpret_cast<const float4*>(ws + 8192);
        #pragma unroll
        for (int it = 0; it < 2; ++it) {
            int i = it * TPB + tid;       // float4 index 0..1023
            int h = i >> 3;
            int dq = (i & 7) << 2;
            *reinterpret_cast<float4*>(&Ms[h][dq]) = m4[i];
            *reinterpret_cast<float4*>(&Ws[h][dq]) = w4[i];
        }
    }
    // y: block slice = 32*33 = 1056 contiguous floats (16B-aligned) = 264 float4
    {
        const float4* yb4 = reinterpret_cast<const float4*>(y + (size_t)blk * BPB * 33);
        if (tid < 264) {
            float4 v = yb4[tid];
            int base = 4 * tid;
            int r0 = base / 33, c0 = base - 33 * r0;
            float vv[4] = { v.x, v.y, v.z, v.w };
            #pragma unroll
            for (int j = 0; j < 4; ++j) {
                int c = c0 + j, r = r0;
                if (c >= 33) { c -= 33; r += 1; }
                xs[r][c] = vv[j];   // col 32 = t-column, harmless
            }
        }
    }
    if (tid >= 264 && tid < 264 + HID) sbias_s[tid - 264] = ws[4096 + (tid - 264)];
    if (tid >= 392 && tid < 392 + D)   b2s[tid - 392] = b2[tid - 392];
    __syncthreads();

    if (tid < HID) {   // c[h] = sum_d M[h,d]*w2T[h,d]
        const float4* mr = reinterpret_cast<const float4*>(&Ms[tid][0]);
        const float4* wr = reinterpret_cast<const float4*>(&Ws[tid][0]);
        float acc = 0.f;
        #pragma unroll
        for (int q = 0; q < 8; ++q) {
            float4 m = mr[q], w = wr[q];
            acc += m.x * w.x + m.y * w.y + m.z * w.z + m.w * w.w;
        }
        cs_s[tid] = acc;
    }

    const int hg   = tid & 31;    // h-group lane: owns h = k*32+hg, k=0..3
    const int pair = tid >> 5;    // 0..15 -> batches 2*pair, 2*pair+1
    const int b0 = 2 * pair, b1 = b0 + 1;

    float xr0[D], xr1[D];
    {
        const float4* x0 = reinterpret_cast<const float4*>(&xs[b0][0]);
        const float4* x1 = reinterpret_cast<const float4*>(&xs[b1][0]);
        #pragma unroll
        for (int q = 0; q < 8; ++q) {
            float4 v0 = x0[q], v1 = x1[q];
            xr0[4*q] = v0.x; xr0[4*q+1] = v0.y; xr0[4*q+2] = v0.z; xr0[4*q+3] = v0.w;
            xr1[4*q] = v1.x; xr1[4*q+1] = v1.y; xr1[4*q+2] = v1.z; xr1[4*q+3] = v1.w;
        }
    }
    __syncthreads();   // cs_s ready

    float dx0[D], dx1[D];
    #pragma unroll
    for (int d = 0; d < D; ++d) { dx0[d] = 0.f; dx1[d] = 0.f; }
    float div0 = 0.f, div1 = 0.f;

    #pragma unroll
    for (int k = 0; k < 4; ++k) {
        const int h = (k << 5) | hg;
        float s0 = sbias_s[h], s1 = s0;
        const float4* mrow = reinterpret_cast<const float4*>(&Ms[h][0]);
        #pragma unroll
        for (int q = 0; q < 8; ++q) {
            float4 m = mrow[q];
            s0 += xr0[4*q]*m.x + xr0[4*q+1]*m.y + xr0[4*q+2]*m.z + xr0[4*q+3]*m.w;
            s1 += xr1[4*q]*m.x + xr1[4*q+1]*m.y + xr1[4*q+2]*m.z + xr1[4*q+3]*m.w;
        }
        // tanh(s) = 1 - 2/(e^{2s}+1); exact at both saturations
        float e0 = __expf(2.f * s0), e1 = __expf(2.f * s1);
        float a0 = 1.f - 2.f / (e0 + 1.f);
        float a1 = 1.f - 2.f / (e1 + 1.f);
        float ch = cs_s[h];
        div0 += (1.f - a0 * a0) * ch;
        div1 += (1.f - a1 * a1) * ch;
        const float4* wrow = reinterpret_cast<const float4*>(&Ws[h][0]);
        #pragma unroll
        for (int q = 0; q < 8; ++q) {
            float4 w = wrow[q];
            dx0[4*q]   += a0 * w.x;  dx1[4*q]   += a1 * w.x;
            dx0[4*q+1] += a0 * w.y;  dx1[4*q+1] += a1 * w.y;
            dx0[4*q+2] += a0 * w.z;  dx1[4*q+2] += a1 * w.z;
            dx0[4*q+3] += a0 * w.w;  dx1[4*q+3] += a1 * w.w;
        }
    }

    // pure-VALU DPP tree reduction over the 32 hg-lanes of this pair
    #pragma unroll
    for (int d = 0; d < D; ++d) {
        dx0[d] = reduce32(dx0[d]);
        dx1[d] = reduce32(dx1[d]);
    }
    div0 = reduce32(div0);
    div1 = reduce32(div1);

    if (hg == 16) {   // lanes 16 & 48 of each wave hold the full group sums
        #pragma unroll
        for (int d = 0; d < D; ++d) {
            os[b0][d] = dx0[d] + b2s[d];
            os[b1][d] = dx1[d] + b2s[d];
        }
        os[b0][D] = -div0;
        os[b1][D] = -div1;
    }
    __syncthreads();

    // coalesced float4 store of the block's 1056 contiguous output floats
    {
        const float4* os4 = reinterpret_cast<const float4*>(&os[0][0]);
        float4* ob4 = reinterpret_cast<float4*>(out + (size_t)blk * BPB * 33);
        if (tid < 264) ob4[tid] = os4[tid];
    }
}

extern "C" void kernel_launch(void* const* d_in, const int* in_sizes, int n_in,
                              void* d_out, int out_size, void* d_ws, size_t ws_size,
                              hipStream_t stream) {
    const float* y   = (const float*)d_in[0];
    const float* t   = (const float*)d_in[1];
    const float* hw1 = (const float*)d_in[2];
    const float* hb1 = (const float*)d_in[3];
    const float* hw2 = (const float*)d_in[4];
    const float* hb2 = (const float*)d_in[5];
    const float* bw  = (const float*)d_in[6];
    const float* bb  = (const float*)d_in[7];
    const float* w2  = (const float*)d_in[8];
    const float* b2  = (const float*)d_in[9];
    float* ws  = (float*)d_ws;
    float* out = (float*)d_out;

    hipLaunchKernelGGL(prep_kernel, dim3(17), dim3(128), 0, stream,
                       t, hw1, hb1, hw2, hb2, bw, bb, w2, ws);
    hipLaunchKernelGGL(main_kernel, dim3(8192 / BPB), dim3(TPB), 0, stream,
                       y, ws, b2, out);
}